// Round 10
// baseline (118.872 us; speedup 1.0000x reference)
//
#include <hip/hip_runtime.h>
#include <math.h>

typedef _Float16 f16;
typedef __attribute__((ext_vector_type(8))) _Float16 f16x8;
typedef __attribute__((ext_vector_type(16))) float f32x16;

// sat (128,4,64,16) f32, grd (128,4,64,16) f32
// out (f32): sat 524288 | grd 524288 | distance[g][s] 16384 | orien[s][g] 16384
#define DIST_OFF  1048576
#define ORI_OFF   1064960
#define SATP_STR  72          // f16 elems per satP row (144 B)
#define RSTR      66          // red j-stride (float2 -> 2-way banks, free)

#define MFMA(a,b,c) __builtin_amdgcn_mfma_f32_32x32x16_f16((a),(b),(c),0,0,0)

// Single fused kernel: prep -> gridsync -> corr -> gridsync -> copies+outputs.
// Grid 256 (1 block/CU: co-resident), 1024 thr = 16 waves. grdF staged in d_out.
__global__ __launch_bounds__(1024, 4) void fused_k(const float* __restrict__ sat,
                                                   const float* __restrict__ grd,
                                                   float* out) {
    __shared__ __align__(16) unsigned char smem[67584];  // prep tiles | satP | red 4x64x66
    __shared__ float wred[16];
    __shared__ float rnormS;

    const int tid  = threadIdx.x;
    const int bi   = blockIdx.x;
    const int wave = tid >> 6, lane = tid & 63;
    const int m = lane & 31, half = lane >> 5;
    const int s  = bi >> 1;
    const int gh = bi & 1;

    unsigned* cnt = (unsigned*)(out + DIST_OFF);   // overwritten by distance at the end
    if (tid == 0) atomicCAS(cnt, 0xAAAAAAAAu, 0u); // poison->0; memset-0 path already 0

    f16* gHi = (f16*)out;                    // staging: floats [0, 262144)
    f16* gLo = (f16*)(out + 262144);         // floats [262144, 524288)

    // ---------- phase A: prep grdF, 1/256 per block (k = dw*64 + h*16 + c) ----------
    {
        f16* tH = (f16*)smem;                // [kb_l 64][g_l 4][e 8] = 2048 f16
        f16* tL = tH + 2048;
        const int g0 = (bi & 31) * 4;
        const int kq = bi >> 5;              // k-range [kq*512, +512)
        #pragma unroll
        for (int i = 0; i < 2; ++i) {
            int flat = i * 1024 + tid;       // [g_l 4][h 4][j 128], coalesced reads
            int g_l = flat >> 9;
            int r   = flat & 511;
            int h   = r >> 7;
            int j   = r & 127;               // dw_l = j>>4, c = j&15
            float v = grd[(((g0 + g_l) * 4 + h) * 64 + kq * 8) * 16 + j];
            int k_l = (j >> 4) * 64 + h * 16 + (j & 15);
            f16 hv = (f16)v;
            int a = (k_l >> 3) * 32 + g_l * 8 + (k_l & 7);
            tH[a] = hv;
            tL[a] = (f16)(v - (float)hv);
        }
        __syncthreads();
        if (tid < 256) {                     // frag f: kb_l = f>>2, g_l = f&3
            int dst = (kq * 64 + (tid >> 2)) * 128 + g0 + (tid & 3);
            ((f16x8*)gHi)[dst] = *(const f16x8*)(tH + tid * 8);
            ((f16x8*)gLo)[dst] = *(const f16x8*)(tL + tid * 8);
        }
        __syncthreads();
    }

    // ---------- stage satP hi/lo (doubled along w) + ||sat[s]||^2 ----------
    f16* sH = (f16*)smem;                    // [w' 0..126][hc 0..63], stride 72
    f16* sL = sH + 127 * SATP_STR;
    float* red = (float*)smem;               // later: [slot 4][g 64][j stride 66]

    const float* satS = sat + s * 4096;
    float ssq = 0.f;
    #pragma unroll
    for (int r = 0; r < 4; ++r) {
        int idx = r * 1024 + tid;
        float v = satS[idx];
        int h = idx >> 10, w = (idx >> 4) & 63, c = idx & 15;
        int col = h * 16 + c;
        f16 hv = (f16)v, lv = (f16)(v - (float)hv);
        sH[w * SATP_STR + col] = hv;
        sL[w * SATP_STR + col] = lv;
        if (w < 63) { sH[(w + 64) * SATP_STR + col] = hv; sL[(w + 64) * SATP_STR + col] = lv; }
        ssq += v * v;
    }
    #pragma unroll
    for (int off = 32; off > 0; off >>= 1) ssq += __shfl_down(ssq, off, 64);
    if (lane == 0) wred[wave] = ssq;
    __syncthreads();
    if (tid == 0) {
        float t = 0.f;
        #pragma unroll
        for (int i = 0; i < 16; ++i) t += wred[i];
        rnormS = 1.f / fmaxf(sqrtf(t), 1e-12f);
    }

    // ---------- grid sync 1: grdF visible device-wide ----------
    __syncthreads();
    if (tid == 0) {
        __threadfence();
        atomicAdd(cnt, 1u);
        for (long it = 0; it < (1L << 22); ++it) {
            if (atomicAdd(cnt, 0u) >= 256u) break;
            __builtin_amdgcn_s_sleep(4);
        }
        __threadfence();
    }
    __syncthreads();

    // ---------- K-loop: 16 waves kh-split, 16 tiles each, 12 MFMA / 8 loads ----------
    const f16* Ah = sH + m * SATP_STR + half * 8;
    const f16* Al = sL + m * SATP_STR + half * 8;
    const f16x8* BH = (const f16x8*)gHi + half * 128 + gh * 64 + m;
    const f16x8* BL = (const f16x8*)gLo + half * 128 + gh * 64 + m;

    f32x16 acc[2][2];
    #pragma unroll
    for (int jt = 0; jt < 2; ++jt)
        #pragma unroll
        for (int gt = 0; gt < 2; ++gt)
            #pragma unroll
            for (int r = 0; r < 16; ++r) acc[jt][gt][r] = 0.f;

    const int t0 = wave * 16;
    #pragma unroll 4
    for (int t = t0; t < t0 + 16; ++t) {
        int ao = (t >> 2) * SATP_STR + (t & 3) * 16;
        f16x8 ah0 = *(const f16x8*)(Ah + ao);
        f16x8 ah1 = *(const f16x8*)(Ah + ao + 32 * SATP_STR);
        f16x8 al0 = *(const f16x8*)(Al + ao);
        f16x8 al1 = *(const f16x8*)(Al + ao + 32 * SATP_STR);
        int bu = t * 256;
        f16x8 bh0 = BH[bu], bh1 = BH[bu + 32];
        f16x8 bl0 = BL[bu], bl1 = BL[bu + 32];
        acc[0][0] = MFMA(ah0, bh0, acc[0][0]);
        acc[0][1] = MFMA(ah0, bh1, acc[0][1]);
        acc[1][0] = MFMA(ah1, bh0, acc[1][0]);
        acc[1][1] = MFMA(ah1, bh1, acc[1][1]);
        acc[0][0] = MFMA(ah0, bl0, acc[0][0]);
        acc[0][1] = MFMA(ah0, bl1, acc[0][1]);
        acc[1][0] = MFMA(ah1, bl0, acc[1][0]);
        acc[1][1] = MFMA(ah1, bl1, acc[1][1]);
        acc[0][0] = MFMA(al0, bh0, acc[0][0]);
        acc[0][1] = MFMA(al0, bh1, acc[0][1]);
        acc[1][0] = MFMA(al1, bh0, acc[1][0]);
        acc[1][1] = MFMA(al1, bh1, acc[1][1]);
    }

    // ---------- reduce: 16 partials -> 4 slots -> slot0 (satP dead) ----------
#define PUT(rp, op) { \
    _Pragma("unroll") for (int jt = 0; jt < 2; ++jt) \
    _Pragma("unroll") for (int gt = 0; gt < 2; ++gt) { \
        float* row = (rp) + (gt * 32 + m) * RSTR + jt * 32 + half * 4; \
        _Pragma("unroll") for (int q = 0; q < 4; ++q) { \
            float2 u = { acc[jt][gt][4*q],   acc[jt][gt][4*q+1] }; \
            float2 v = { acc[jt][gt][4*q+2], acc[jt][gt][4*q+3] }; \
            op(row + q * 8, u, v); } } }
#define OPW(p, u, v)  { *(float2*)(p) = u; *(float2*)((p) + 2) = v; }
#define OPA(p, u, v)  { float2 a = *(float2*)(p), b = *(float2*)((p) + 2); \
                        a.x += u.x; a.y += u.y; b.x += v.x; b.y += v.y; \
                        *(float2*)(p) = a; *(float2*)((p) + 2) = b; }

    __syncthreads();
    if (wave >= 12) PUT(red + (wave - 12) * 4224, OPW)
    __syncthreads();
    if (wave >= 8 && wave < 12) PUT(red + (wave - 8) * 4224, OPA)
    __syncthreads();
    if (wave >= 4 && wave < 8) PUT(red + (wave - 4) * 4224, OPA)
    __syncthreads();
    if (wave < 4) PUT(red + wave * 4224, OPA)
    __syncthreads();
    {
        int g = tid >> 4, q4 = (tid & 15) * 4;       // 64 g x 16 j-quads
        int base = g * RSTR + q4;
        float2 u = {0.f, 0.f}, v = {0.f, 0.f};
        #pragma unroll
        for (int k = 0; k < 4; ++k) {
            float2 a = *(const float2*)(red + k * 4224 + base);
            float2 b = *(const float2*)(red + k * 4224 + base + 2);
            u.x += a.x; u.y += a.y; v.x += b.x; v.y += b.y;
        }
        *(float2*)(red + base) = u;                  // own cells only: race-free
        *(float2*)(red + base + 2) = v;
    }
    __syncthreads();

    // ---------- argmax over j (first occurrence) -> registers ----------
    float distV = 0.f, oriV = 0.f;
    if (tid < 64) {
        const float* row = red + tid * RSTR;
        float best = row[0];
        int bj = 0;
        for (int j = 1; j < 64; ++j) {
            float v = row[j];
            if (v > best) { best = v; bj = j; }
        }
        distV = 2.f - 2.f * best * rnormS;
        oriV  = (float)bj;
    }

    // ---------- grid sync 2: all grdF reads done (staging region now dead) ----------
    __syncthreads();
    if (tid == 0) {
        __threadfence();
        atomicAdd(cnt, 1u);
        for (long it = 0; it < (1L << 22); ++it) {
            if (atomicAdd(cnt, 0u) >= 512u) break;
            __builtin_amdgcn_s_sleep(4);
        }
        __threadfence();
    }
    __syncthreads();

    // ---------- passthrough copies (overwrite staging), then distance/orien ----------
    if (tid < 512) {
        int i = bi * 512 + tid;                      // 131072 float4 per tensor
        ((float4*)out)[i] = ((const float4*)sat)[i];
        ((float4*)out)[131072 + i] = ((const float4*)grd)[i];
    }
    if (tid < 64) {
        int gg = gh * 64 + tid;
        out[DIST_OFF + gg * 128 + s] = distV;        // overwrites counter cell last
        out[ORI_OFF + s * 128 + gg]  = oriV;
    }
}

extern "C" void kernel_launch(void* const* d_in, const int* in_sizes, int n_in,
                              void* d_out, int out_size, void* d_ws, size_t ws_size,
                              hipStream_t stream) {
    const float* sat = (const float*)d_in[0];
    const float* grd = (const float*)d_in[1];
    float* out = (float*)d_out;
    // d_ws unused; grdF staged in d_out's passthrough region, freed by the copies.
    fused_k<<<256, 1024, 0, stream>>>(sat, grd, out);
}